// Round 5
// baseline (92.379 us; speedup 1.0000x reference)
//
#include <hip/hip_runtime.h>

namespace {
constexpr int Hh = 16;
constexpr int Ll = 1024;
constexpr int Dd = 64;
constexpr int Cc = 64;                   // chunk length
constexpr int NCHUNK = Ll / Cc;          // 16
constexpr float PI_HALF = 1.5707963267948966f;
constexpr float EPSV = 1e-6f;
}

typedef __attribute__((ext_vector_type(8))) short short8;
typedef __attribute__((ext_vector_type(4))) float floatx4;

__device__ __forceinline__ unsigned short f2bf(float x) {
    unsigned int u = __float_as_uint(x);
    unsigned int r = u + 0x7fffu + ((u >> 16) & 1u);
    return (unsigned short)(r >> 16);
}

// ---------------------------------------------------------------------------
// Kernel P: one-time feature-map + transpose into ws (bf16):
//   kfT[h][f=128][j=1024], vT[h][d=64][j=1024]   (verified in round 4)
__global__ __launch_bounds__(256)
void cf_prep(const float* __restrict__ kin, const float* __restrict__ vin,
             unsigned short* __restrict__ kfT, unsigned short* __restrict__ vT) {
    const int jt = blockIdx.x, h = blockIdx.y;
    const int tid = threadIdx.x;
    constexpr int S1 = 72;
    __shared__ unsigned short AkT[128 * S1];
    __shared__ unsigned short Vt[64 * S1];

    const size_t gbase = ((size_t)h * Ll + (size_t)jt * Cc) * Dd;
    const float4* k4 = (const float4*)(kin + gbase);
    const float4* v4 = (const float4*)(vin + gbase);
    #pragma unroll
    for (int i = 0; i < 4; ++i) {
        int e4 = i * 256 + tid;
        int j = e4 >> 4, d4 = (e4 & 15) * 4;
        float th = PI_HALF * (float)(jt * Cc + j + 1) * (1.0f / (float)Ll);
        float sj, cj; __sincosf(th, &sj, &cj);
        float4 kx = k4[e4];
        float r0 = fmaxf(kx.x, 0.f), r1 = fmaxf(kx.y, 0.f);
        float r2 = fmaxf(kx.z, 0.f), r3 = fmaxf(kx.w, 0.f);
        AkT[(d4 + 0) * S1 + j] = f2bf(r0 * sj);
        AkT[(d4 + 1) * S1 + j] = f2bf(r1 * sj);
        AkT[(d4 + 2) * S1 + j] = f2bf(r2 * sj);
        AkT[(d4 + 3) * S1 + j] = f2bf(r3 * sj);
        AkT[(64 + d4 + 0) * S1 + j] = f2bf(r0 * cj);
        AkT[(64 + d4 + 1) * S1 + j] = f2bf(r1 * cj);
        AkT[(64 + d4 + 2) * S1 + j] = f2bf(r2 * cj);
        AkT[(64 + d4 + 3) * S1 + j] = f2bf(r3 * cj);
        float4 vx = v4[e4];
        Vt[(d4 + 0) * S1 + j] = f2bf(vx.x);
        Vt[(d4 + 1) * S1 + j] = f2bf(vx.y);
        Vt[(d4 + 2) * S1 + j] = f2bf(vx.z);
        Vt[(d4 + 3) * S1 + j] = f2bf(vx.w);
    }
    __syncthreads();

    unsigned short* kout = kfT + (size_t)h * 128 * Ll + jt * Cc;
    #pragma unroll
    for (int i = 0; i < 4; ++i) {                 // 128 rows x 8 uint4 = 1024 uint4
        int idx = i * 256 + tid;
        int row = idx >> 3, c8 = (idx & 7) * 8;
        *(uint4*)(kout + (size_t)row * Ll + c8) = *(const uint4*)&AkT[row * S1 + c8];
    }
    unsigned short* vout = vT + (size_t)h * 64 * Ll + jt * Cc;
    #pragma unroll
    for (int i = 0; i < 2; ++i) {                 // 64 rows x 8 uint4 = 512 uint4
        int idx = i * 256 + tid;
        int row = idx >> 3, c8 = (idx & 7) * 8;
        *(uint4*)(vout + (size_t)row * Ll + c8) = *(const uint4*)&Vt[row * S1 + c8];
    }
}

// ---------------------------------------------------------------------------
// Kernel M (512 threads, 8 waves): wave = (wavef = wave&3 -> f-pair,
// waveK = wave>>2 -> K-half). Prefix-state GEMM with 2-deep register
// prefetch and 2x latency hiding (2 waves/SIMD); K-half partials reduced
// in fp32 via LDS (stride-41, conflict-free), aliased over Aq (dead until
// staging). Epilogue = round-4-verified GEMM1/GEMM2 on waves 0-3.
__global__ __launch_bounds__(512)
void cf_main(const float* __restrict__ qin, const float* __restrict__ kin,
             const unsigned short* __restrict__ kfT,
             const unsigned short* __restrict__ vT,
             float* __restrict__ out) {
    const int c = blockIdx.x, h = blockIdx.y;
    const int tid = threadIdx.x;
    constexpr int SA = 200, SB = 136, SV = 200;
    // single pool; red (10496 f32 = 20992 shorts) aliases Aq + low Bk rows,
    // all dead until the staging phase (after the reduce barriers).
    __shared__ unsigned short SM[64 * SA + 80 * SB + 64 * SV];
    unsigned short* Aq = SM;                     // [l][0..63 scores | 64..191 qf]
    unsigned short* Bk = SM + 64 * SA;           // [j][f]; row 64 = ksum; 65..79 = 0
    unsigned short* Bv = SM + 64 * SA + 80 * SB; // [d][0..63 V^T | 64..191 S]
    float* red = (float*)SM;                     // [wavef*64+lane][41] fp32

    const int wave = tid >> 6, lane = tid & 63;
    const int lrow = lane & 15, quad = lane >> 4;
    const int wavef = wave & 3, waveK = wave >> 2;

    const unsigned short* At = kfT + (size_t)h * 128 * Ll;
    const unsigned short* Bt = vT + (size_t)h * 64 * Ll;
    const size_t gbase = ((size_t)h * Ll + (size_t)c * Cc) * Dd;

    // -- prefetch epilogue staging data into registers (latency hides under prefix)
    const float4* q4 = (const float4*)(qin + gbase);
    const float4* k4 = (const float4*)(kin + gbase);
    float4 qr[2], kr[2];
    qr[0] = q4[tid]; qr[1] = q4[512 + tid];
    kr[0] = k4[tid]; kr[1] = k4[512 + tid];
    uint4 vr = *(const uint4*)(Bt + c * Cc + (size_t)(tid >> 3) * Ll + (tid & 7) * 8);

    // ---- prefix state GEMM (K-split across waveK, 2-deep prefetch) ----
    floatx4 acc[2][5];
    #pragma unroll
    for (int t = 0; t < 2; ++t)
        #pragma unroll
        for (int nt = 0; nt < 5; ++nt)
            acc[t][nt] = (floatx4){0.f, 0.f, 0.f, 0.f};

    short8 bones;
    {
        short o = (lrow == 0) ? (short)0x3F80 : (short)0;
        #pragma unroll
        for (int i = 0; i < 8; ++i) bones[i] = o;
    }
    const int nk = c * Cc;
    const int a0 = (wavef * 32 + lrow) * Ll + quad * 8;
    const int a1 = a0 + 16 * Ll;
    const int br0 = lrow * Ll + quad * 8;
    const int br1 = br0 + 16 * Ll;
    const int br2 = br0 + 32 * Ll;
    const int br3 = br0 + 48 * Ll;

    int kk = waveK * 32;                      // this wave's K-steps: stride 64
    if (kk < nk) {
        // set0 @ kk, set1 @ kk+64 (overshoot reads stay inside ws; values unused)
        short8 Aa0 = *(const short8*)(At + a0 + kk);
        short8 Aa1 = *(const short8*)(At + a1 + kk);
        short8 Ab0 = *(const short8*)(Bt + br0 + kk);
        short8 Ab1 = *(const short8*)(Bt + br1 + kk);
        short8 Ab2 = *(const short8*)(Bt + br2 + kk);
        short8 Ab3 = *(const short8*)(Bt + br3 + kk);
        short8 Ba0 = *(const short8*)(At + a0 + kk + 64);
        short8 Ba1 = *(const short8*)(At + a1 + kk + 64);
        short8 Bb0 = *(const short8*)(Bt + br0 + kk + 64);
        short8 Bb1 = *(const short8*)(Bt + br1 + kk + 64);
        short8 Bb2 = *(const short8*)(Bt + br2 + kk + 64);
        short8 Bb3 = *(const short8*)(Bt + br3 + kk + 64);
        for (; kk < nk; kk += 64) {
            short8 Ca0 = *(const short8*)(At + a0 + kk + 128);
            short8 Ca1 = *(const short8*)(At + a1 + kk + 128);
            short8 Cb0 = *(const short8*)(Bt + br0 + kk + 128);
            short8 Cb1 = *(const short8*)(Bt + br1 + kk + 128);
            short8 Cb2 = *(const short8*)(Bt + br2 + kk + 128);
            short8 Cb3 = *(const short8*)(Bt + br3 + kk + 128);
            acc[0][0] = __builtin_amdgcn_mfma_f32_16x16x32_bf16(Aa0, Ab0, acc[0][0], 0, 0, 0);
            acc[0][1] = __builtin_amdgcn_mfma_f32_16x16x32_bf16(Aa0, Ab1, acc[0][1], 0, 0, 0);
            acc[0][2] = __builtin_amdgcn_mfma_f32_16x16x32_bf16(Aa0, Ab2, acc[0][2], 0, 0, 0);
            acc[0][3] = __builtin_amdgcn_mfma_f32_16x16x32_bf16(Aa0, Ab3, acc[0][3], 0, 0, 0);
            acc[0][4] = __builtin_amdgcn_mfma_f32_16x16x32_bf16(Aa0, bones, acc[0][4], 0, 0, 0);
            acc[1][0] = __builtin_amdgcn_mfma_f32_16x16x32_bf16(Aa1, Ab0, acc[1][0], 0, 0, 0);
            acc[1][1] = __builtin_amdgcn_mfma_f32_16x16x32_bf16(Aa1, Ab1, acc[1][1], 0, 0, 0);
            acc[1][2] = __builtin_amdgcn_mfma_f32_16x16x32_bf16(Aa1, Ab2, acc[1][2], 0, 0, 0);
            acc[1][3] = __builtin_amdgcn_mfma_f32_16x16x32_bf16(Aa1, Ab3, acc[1][3], 0, 0, 0);
            acc[1][4] = __builtin_amdgcn_mfma_f32_16x16x32_bf16(Aa1, bones, acc[1][4], 0, 0, 0);
            Aa0 = Ba0; Aa1 = Ba1; Ab0 = Bb0; Ab1 = Bb1; Ab2 = Bb2; Ab3 = Bb3;
            Ba0 = Ca0; Ba1 = Ca1; Bb0 = Cb0; Bb1 = Cb1; Bb2 = Cb2; Bb3 = Cb3;
        }
    }

    // ---- cross-wave reduce of K-half partials (fp32, via red/LDS) ----
    if (waveK == 1) {
        float* r = red + (wavef * 64 + lane) * 41;
        #pragma unroll
        for (int t = 0; t < 2; ++t)
            #pragma unroll
            for (int nt = 0; nt < 5; ++nt)
                #pragma unroll
                for (int rr = 0; rr < 4; ++rr)
                    r[t * 20 + nt * 4 + rr] = acc[t][nt][rr];
    }
    __syncthreads();
    if (waveK == 0) {
        const float* r = red + (wavef * 64 + lane) * 41;
        #pragma unroll
        for (int t = 0; t < 2; ++t)
            #pragma unroll
            for (int nt = 0; nt < 5; ++nt)
                #pragma unroll
                for (int rr = 0; rr < 4; ++rr)
                    acc[t][nt][rr] += r[t * 20 + nt * 4 + rr];
    }
    __syncthreads();   // red reads done; Aq/Bk regions now free for staging

    // ---- staging (512 threads) ----
    #pragma unroll
    for (int i = 0; i < 2; ++i) {                 // zero Bk rows 65..79
        int z = i * 512 + tid;
        if (z < 1020) ((unsigned int*)Bk)[(65 * SB) / 2 + z] = 0u;
    }
    #pragma unroll
    for (int i = 0; i < 2; ++i) {
        int e4 = i * 512 + tid;
        int j = e4 >> 4, d4 = (e4 & 15) * 4;
        float th = PI_HALF * (float)(c * Cc + j + 1) * (1.0f / (float)Ll);
        float sj, cj; __sincosf(th, &sj, &cj);
        float4 qv = qr[i];
        float q0 = fmaxf(qv.x, 0.f), q1 = fmaxf(qv.y, 0.f);
        float q2 = fmaxf(qv.z, 0.f), q3 = fmaxf(qv.w, 0.f);
        *(ushort4*)&Aq[j * SA + 64 + d4] =
            make_ushort4(f2bf(q0 * sj), f2bf(q1 * sj), f2bf(q2 * sj), f2bf(q3 * sj));
        *(ushort4*)&Aq[j * SA + 128 + d4] =
            make_ushort4(f2bf(q0 * cj), f2bf(q1 * cj), f2bf(q2 * cj), f2bf(q3 * cj));
        float4 kx = kr[i];
        float k0 = fmaxf(kx.x, 0.f), k1 = fmaxf(kx.y, 0.f);
        float k2 = fmaxf(kx.z, 0.f), k3 = fmaxf(kx.w, 0.f);
        *(ushort4*)&Bk[j * SB + d4] =
            make_ushort4(f2bf(k0 * sj), f2bf(k1 * sj), f2bf(k2 * sj), f2bf(k3 * sj));
        *(ushort4*)&Bk[j * SB + 64 + d4] =
            make_ushort4(f2bf(k0 * cj), f2bf(k1 * cj), f2bf(k2 * cj), f2bf(k3 * cj));
    }
    *(uint4*)&Bv[(tid >> 3) * SV + (tid & 7) * 8] = vr;   // V^T cols 0..63

    // dump final state S[f][d] -> Bv[d][64+f], ksum -> Bk row 64 (waves 0-3)
    if (waveK == 0) {
        #pragma unroll
        for (int t = 0; t < 2; ++t) {
            const int ft = wavef * 2 + t;
            #pragma unroll
            for (int nt = 0; nt < 4; ++nt) {
                *(ushort4*)&Bv[(nt * 16 + lrow) * SV + 64 + ft * 16 + quad * 4] =
                    make_ushort4(f2bf(acc[t][nt][0]), f2bf(acc[t][nt][1]),
                                 f2bf(acc[t][nt][2]), f2bf(acc[t][nt][3]));
            }
            if (lrow == 0)
                *(ushort4*)&Bk[64 * SB + ft * 16 + quad * 4] =
                    make_ushort4(f2bf(acc[t][4][0]), f2bf(acc[t][4][1]),
                                 f2bf(acc[t][4][2]), f2bf(acc[t][4][3]));
        }
    }
    __syncthreads();

    // ---- GEMM1: scores + denominator (waves 0-3) ----
    const int l0 = wavef * 16;
    const int arow = (l0 + lrow) * SA;
    short8 a1f[4];
    float inv[4];
    if (waveK == 0) {
        #pragma unroll
        for (int ks = 0; ks < 4; ++ks)
            a1f[ks] = *(const short8*)&Aq[arow + 64 + ks * 32 + quad * 8];
        floatx4 rs = {0.f, 0.f, 0.f, 0.f};
        #pragma unroll
        for (int nt = 0; nt < 5; ++nt) {
            floatx4 sc = {0.f, 0.f, 0.f, 0.f};
            #pragma unroll
            for (int ks = 0; ks < 4; ++ks) {
                short8 bf = *(const short8*)&Bk[(nt * 16 + lrow) * SB + ks * 32 + quad * 8];
                sc = __builtin_amdgcn_mfma_f32_16x16x32_bf16(a1f[ks], bf, sc, 0, 0, 0);
            }
            if (nt < 4) {
                int j = nt * 16 + lrow;
                #pragma unroll
                for (int r = 0; r < 4; ++r) {
                    int l = l0 + quad * 4 + r;
                    float m = (j <= l) ? sc[r] : 0.f;
                    sc[r] = m;
                    Aq[l * SA + j] = f2bf(m);      // masked score -> A for GEMM2
                }
            }
            rs += sc;                               // nt==4: rows 65..79 exact zeros
        }
        #pragma unroll
        for (int m = 1; m <= 8; m <<= 1) {
            rs[0] += __shfl_xor(rs[0], m);
            rs[1] += __shfl_xor(rs[1], m);
            rs[2] += __shfl_xor(rs[2], m);
            rs[3] += __shfl_xor(rs[3], m);
        }
        #pragma unroll
        for (int r = 0; r < 4; ++r) inv[r] = 1.0f / fmaxf(rs[r], EPSV);
    }
    __syncthreads();   // score writes visible

    // ---- GEMM2: O = [scores | qf] * [V ; S] (waves 0-3) ----
    if (waveK == 0) {
        short8 sc0 = *(const short8*)&Aq[arow + 0 * 32 + quad * 8];
        short8 sc1 = *(const short8*)&Aq[arow + 1 * 32 + quad * 8];
        #pragma unroll
        for (int nt = 0; nt < 4; ++nt) {
            const int brow = (nt * 16 + lrow) * SV;
            floatx4 oacc = {0.f, 0.f, 0.f, 0.f};
            short8 b0 = *(const short8*)&Bv[brow + 0 * 32 + quad * 8];
            oacc = __builtin_amdgcn_mfma_f32_16x16x32_bf16(sc0, b0, oacc, 0, 0, 0);
            short8 b1 = *(const short8*)&Bv[brow + 1 * 32 + quad * 8];
            oacc = __builtin_amdgcn_mfma_f32_16x16x32_bf16(sc1, b1, oacc, 0, 0, 0);
            #pragma unroll
            for (int ks = 2; ks < 6; ++ks) {
                short8 bf = *(const short8*)&Bv[brow + ks * 32 + quad * 8];
                oacc = __builtin_amdgcn_mfma_f32_16x16x32_bf16(a1f[ks - 2], bf, oacc, 0, 0, 0);
            }
            #pragma unroll
            for (int r = 0; r < 4; ++r) {
                int l = l0 + quad * 4 + r;
                out[gbase + (size_t)l * Dd + nt * 16 + lrow] = oacc[r] * inv[r];
            }
        }
    }
}

extern "C" void kernel_launch(void* const* d_in, const int* in_sizes, int n_in,
                              void* d_out, int out_size, void* d_ws, size_t ws_size,
                              hipStream_t stream) {
    const float* q = (const float*)d_in[0];
    const float* k = (const float*)d_in[1];
    const float* v = (const float*)d_in[2];
    float* out = (float*)d_out;
    unsigned short* kfT = (unsigned short*)d_ws;                  // [h][128][1024] bf16
    unsigned short* vT = kfT + (size_t)Hh * 128 * Ll;             // [h][64][1024] bf16
    dim3 grid(NCHUNK, Hh);
    cf_prep<<<grid, 256, 0, stream>>>(k, v, kfT, vT);
    cf_main<<<grid, 512, 0, stream>>>(q, k, kfT, vT, out);
}

// Round 6
// 83.458 us; speedup vs baseline: 1.1069x; 1.1069x over previous
//
#include <hip/hip_runtime.h>

namespace {
constexpr int Hh = 16;
constexpr int Ll = 1024;
constexpr int Dd = 64;
constexpr int Cc = 64;                   // chunk length
constexpr int NCHUNK = Ll / Cc;          // 16
constexpr float PI_HALF = 1.5707963267948966f;
constexpr float EPSV = 1e-6f;
}

typedef __attribute__((ext_vector_type(8))) short short8;
typedef __attribute__((ext_vector_type(4))) float floatx4;

__device__ __forceinline__ unsigned short f2bf(float x) {
    unsigned int u = __float_as_uint(x);
    unsigned int r = u + 0x7fffu + ((u >> 16) & 1u);
    return (unsigned short)(r >> 16);
}

typedef __attribute__((address_space(3))) unsigned int lds_u32_t;
typedef __attribute__((address_space(1))) unsigned int glb_u32_t;

// async global->LDS, 16 B per lane; LDS dest = wave-uniform base + lane*16
__device__ __forceinline__ void gld16(const unsigned short* g, unsigned short* l) {
    __builtin_amdgcn_global_load_lds((const glb_u32_t*)g, (lds_u32_t*)l, 16, 0, 0);
}

#define MFMA16(a, b, c) __builtin_amdgcn_mfma_f32_16x16x32_bf16((a), (b), (c), 0, 0, 0)

// ---------------------------------------------------------------------------
// Kernel P: one-time feature-map + transpose into ws (bf16), verified r4:
//   kfT[h][f=128][j=1024], vT[h][d=64][j=1024]
__global__ __launch_bounds__(256)
void cf_prep(const float* __restrict__ kin, const float* __restrict__ vin,
             unsigned short* __restrict__ kfT, unsigned short* __restrict__ vT) {
    const int jt = blockIdx.x, h = blockIdx.y;
    const int tid = threadIdx.x;
    constexpr int S1 = 72;
    __shared__ unsigned short AkT[128 * S1];
    __shared__ unsigned short Vt[64 * S1];

    const size_t gbase = ((size_t)h * Ll + (size_t)jt * Cc) * Dd;
    const float4* k4 = (const float4*)(kin + gbase);
    const float4* v4 = (const float4*)(vin + gbase);
    #pragma unroll
    for (int i = 0; i < 4; ++i) {
        int e4 = i * 256 + tid;
        int j = e4 >> 4, d4 = (e4 & 15) * 4;
        float th = PI_HALF * (float)(jt * Cc + j + 1) * (1.0f / (float)Ll);
        float sj, cj; __sincosf(th, &sj, &cj);
        float4 kx = k4[e4];
        float r0 = fmaxf(kx.x, 0.f), r1 = fmaxf(kx.y, 0.f);
        float r2 = fmaxf(kx.z, 0.f), r3 = fmaxf(kx.w, 0.f);
        AkT[(d4 + 0) * S1 + j] = f2bf(r0 * sj);
        AkT[(d4 + 1) * S1 + j] = f2bf(r1 * sj);
        AkT[(d4 + 2) * S1 + j] = f2bf(r2 * sj);
        AkT[(d4 + 3) * S1 + j] = f2bf(r3 * sj);
        AkT[(64 + d4 + 0) * S1 + j] = f2bf(r0 * cj);
        AkT[(64 + d4 + 1) * S1 + j] = f2bf(r1 * cj);
        AkT[(64 + d4 + 2) * S1 + j] = f2bf(r2 * cj);
        AkT[(64 + d4 + 3) * S1 + j] = f2bf(r3 * cj);
        float4 vx = v4[e4];
        Vt[(d4 + 0) * S1 + j] = f2bf(vx.x);
        Vt[(d4 + 1) * S1 + j] = f2bf(vx.y);
        Vt[(d4 + 2) * S1 + j] = f2bf(vx.z);
        Vt[(d4 + 3) * S1 + j] = f2bf(vx.w);
    }
    __syncthreads();

    unsigned short* kout = kfT + (size_t)h * 128 * Ll + jt * Cc;
    #pragma unroll
    for (int i = 0; i < 4; ++i) {                 // 128 rows x 8 uint4 = 1024 uint4
        int idx = i * 256 + tid;
        int row = idx >> 3, c8 = (idx & 7) * 8;
        *(uint4*)(kout + (size_t)row * Ll + c8) = *(const uint4*)&AkT[row * S1 + c8];
    }
    unsigned short* vout = vT + (size_t)h * 64 * Ll + jt * Cc;
    #pragma unroll
    for (int i = 0; i < 2; ++i) {                 // 64 rows x 8 uint4 = 512 uint4
        int idx = i * 256 + tid;
        int row = idx >> 3, c8 = (idx & 7) * 8;
        *(uint4*)(vout + (size_t)row * Ll + c8) = *(const uint4*)&Vt[row * S1 + c8];
    }
}

// ---------------------------------------------------------------------------
// Kernel M: one block per (h,c). Prefix-state GEMM now staged through LDS
// with global_load_lds(16B), 3 buffers, 2-ahead counted vmcnt(6) pipeline
// (~48 KB in flight per CU vs 1.5 KB register-prefetch in r4/r5 — the MLP
// fix). XOR block swizzle (col16 ^= row&7) applied on the GLOBAL source
// (LDS dest linear per G21) and mirrored on ds_read (G4 conflict fix).
// MFMA accumulation order identical to verified r4. Epilogue = r4 verbatim.
__global__ __launch_bounds__(256)
void cf_main(const float* __restrict__ qin, const float* __restrict__ kin,
             const unsigned short* __restrict__ kfT,
             const unsigned short* __restrict__ vT,
             float* __restrict__ out) {
    const int c = blockIdx.x, h = blockIdx.y;
    const int tid = threadIdx.x;
    constexpr int SA = 200, SB = 136, SV = 200;
    __shared__ unsigned short Aq[64 * SA];   // [l][0..63 scores | 64..191 qf]
    __shared__ unsigned short Bk[80 * SB];   // [n=j][k=f]; row 64 = ksum; 65..79 = 0
    __shared__ unsigned short Bv[64 * SV];   // [n=d][0..63 V^T | 64..191 S]
    // staging: per buffer A[128][64] then B[64][64] shorts (24 KB); 3 buffers
    __shared__ unsigned short Sta[3][192 * 64];

    const int wave = tid >> 6, lane = tid & 63;
    const int lrow = lane & 15, quad = lane >> 4;

    #pragma unroll
    for (int i = 0; i < 4; ++i) {            // zero Bk rows 65..79
        int z = i * 256 + tid;
        if (z < 1020) ((unsigned int*)Bk)[(65 * SB) / 2 + z] = 0u;
    }

    floatx4 acc[2][5];
    #pragma unroll
    for (int t = 0; t < 2; ++t)
        #pragma unroll
        for (int nt = 0; nt < 5; ++nt)
            acc[t][nt] = (floatx4){0.f, 0.f, 0.f, 0.f};

    const unsigned short* At = kfT + (size_t)h * 128 * Ll;
    const unsigned short* Bt = vT + (size_t)h * 64 * Ll;
    short8 bones;
    {
        short o = (lrow == 0) ? (short)0x3F80 : (short)0;
        #pragma unroll
        for (int i = 0; i < 8; ++i) bones[i] = o;
    }

    // ---- prefix state GEMM, LDS-pipelined ----
    auto STAGE = [&](int buf, int tile) {
        const int kk = tile * 64;
        unsigned short* SA_ = &Sta[buf][0];
        unsigned short* SB_ = &Sta[buf][128 * 64];
        #pragma unroll
        for (int i = 0; i < 4; ++i) {        // A: 128 rows x 8 blocks of 16 B
            int g = i * 256 + tid;
            int r = g >> 3, cb = g & 7;
            gld16(At + (size_t)r * Ll + kk + ((cb ^ (r & 7)) << 3), SA_ + g * 8);
        }
        #pragma unroll
        for (int i = 0; i < 2; ++i) {        // B: 64 rows x 8 blocks of 16 B
            int g = i * 256 + tid;
            int r = g >> 3, cb = g & 7;
            gld16(Bt + (size_t)r * Ll + kk + ((cb ^ (r & 7)) << 3), SB_ + g * 8);
        }
    };
    auto COMPUTE = [&](int buf) {
        const unsigned short* SA_ = &Sta[buf][0];
        const unsigned short* SB_ = &Sta[buf][128 * 64];
        const int sw = lrow & 7;
        const int r0 = wave * 32 + lrow, r1 = r0 + 16;
        #pragma unroll
        for (int ks = 0; ks < 2; ++ks) {
            const int cb = ((ks * 4 + quad) ^ sw) << 3;
            short8 a0 = *(const short8*)&SA_[r0 * 64 + cb];
            short8 a1 = *(const short8*)&SA_[r1 * 64 + cb];
            #pragma unroll
            for (int nt = 0; nt < 4; ++nt) {
                short8 b = *(const short8*)&SB_[(nt * 16 + lrow) * 64 + cb];
                acc[0][nt] = MFMA16(a0, b, acc[0][nt]);
                acc[1][nt] = MFMA16(a1, b, acc[1][nt]);
            }
            acc[0][4] = MFMA16(a0, bones, acc[0][4]);
            acc[1][4] = MFMA16(a1, bones, acc[1][4]);
        }
    };

    const int ntile = c;                     // K-tiles of 64 (exclusive prefix)
    if (ntile >= 1) {
        STAGE(0, 0);
        if (ntile >= 2) {
            STAGE(1, 1);
            asm volatile("s_waitcnt vmcnt(6)" ::: "memory");
        } else {
            asm volatile("s_waitcnt vmcnt(0)" ::: "memory");
        }
        __builtin_amdgcn_s_barrier();
        asm volatile("" ::: "memory");
        for (int t = 0; t < ntile; ++t) {
            const bool more = (t + 2) < ntile;
            if (more) STAGE((t + 2) % 3, t + 2);
            COMPUTE(t % 3);
            if (more) asm volatile("s_waitcnt vmcnt(6)" ::: "memory");
            else      asm volatile("s_waitcnt vmcnt(0)" ::: "memory");
            __builtin_amdgcn_s_barrier();
            asm volatile("" ::: "memory");
        }
    }

    // ---- epilogue (r4 verbatim): stage own chunk, dump state, GEMM1+GEMM2 --
    const size_t gbase = ((size_t)h * Ll + (size_t)c * Cc) * Dd;
    const float4* q4 = (const float4*)(qin + gbase);
    const float4* k4 = (const float4*)(kin + gbase);
    #pragma unroll
    for (int i = 0; i < 4; ++i) {
        int e4 = i * 256 + tid;
        int j = e4 >> 4, d4 = (e4 & 15) * 4;
        float th = PI_HALF * (float)(c * Cc + j + 1) * (1.0f / (float)Ll);
        float sj, cj; __sincosf(th, &sj, &cj);
        float4 qv = q4[e4];
        float q0 = fmaxf(qv.x, 0.f), q1 = fmaxf(qv.y, 0.f);
        float q2 = fmaxf(qv.z, 0.f), q3 = fmaxf(qv.w, 0.f);
        *(ushort4*)&Aq[j * SA + 64 + d4] =
            make_ushort4(f2bf(q0 * sj), f2bf(q1 * sj), f2bf(q2 * sj), f2bf(q3 * sj));
        *(ushort4*)&Aq[j * SA + 128 + d4] =
            make_ushort4(f2bf(q0 * cj), f2bf(q1 * cj), f2bf(q2 * cj), f2bf(q3 * cj));
        float4 kx = k4[e4];
        float k0 = fmaxf(kx.x, 0.f), k1 = fmaxf(kx.y, 0.f);
        float k2 = fmaxf(kx.z, 0.f), k3 = fmaxf(kx.w, 0.f);
        *(ushort4*)&Bk[j * SB + d4] =
            make_ushort4(f2bf(k0 * sj), f2bf(k1 * sj), f2bf(k2 * sj), f2bf(k3 * sj));
        *(ushort4*)&Bk[j * SB + 64 + d4] =
            make_ushort4(f2bf(k0 * cj), f2bf(k1 * cj), f2bf(k2 * cj), f2bf(k3 * cj));
    }
    // Bv cols 0..63 = V^T of own chunk, straight bf16 copy from vT
    const unsigned short* vsrc = Bt + c * Cc;
    #pragma unroll
    for (int i = 0; i < 2; ++i) {                 // 64 rows x 8 uint4 = 512 uint4
        int idx = i * 256 + tid;
        int d = idx >> 3, j8 = (idx & 7) * 8;
        *(uint4*)&Bv[d * SV + j8] = *(const uint4*)(vsrc + (size_t)d * Ll + j8);
    }
    // dump exclusive state S[f][d] -> Bv[d][64+f] (bf16), ksum -> Bk row 64
    #pragma unroll
    for (int t = 0; t < 2; ++t) {
        const int ft = wave * 2 + t;
        #pragma unroll
        for (int nt = 0; nt < 4; ++nt) {
            *(ushort4*)&Bv[(nt * 16 + lrow) * SV + 64 + ft * 16 + quad * 4] =
                make_ushort4(f2bf(acc[t][nt][0]), f2bf(acc[t][nt][1]),
                             f2bf(acc[t][nt][2]), f2bf(acc[t][nt][3]));
        }
        if (lrow == 0)
            *(ushort4*)&Bk[64 * SB + ft * 16 + quad * 4] =
                make_ushort4(f2bf(acc[t][4][0]), f2bf(acc[t][4][1]),
                             f2bf(acc[t][4][2]), f2bf(acc[t][4][3]));
    }
    __syncthreads();

    const int l0 = wave * 16;
    const int arow = (l0 + lrow) * SA;

    // GEMM1: scores + denominator
    short8 a1f[4];
    #pragma unroll
    for (int ks = 0; ks < 4; ++ks)
        a1f[ks] = *(const short8*)&Aq[arow + 64 + ks * 32 + quad * 8];
    floatx4 rs = {0.f, 0.f, 0.f, 0.f};
    #pragma unroll
    for (int nt = 0; nt < 5; ++nt) {
        floatx4 sc = {0.f, 0.f, 0.f, 0.f};
        #pragma unroll
        for (int ks = 0; ks < 4; ++ks) {
            short8 bf = *(const short8*)&Bk[(nt * 16 + lrow) * SB + ks * 32 + quad * 8];
            sc = MFMA16(a1f[ks], bf, sc);
        }
        if (nt < 4) {
            int j = nt * 16 + lrow;
            #pragma unroll
            for (int r = 0; r < 4; ++r) {
                int l = l0 + quad * 4 + r;
                float m = (j <= l) ? sc[r] : 0.f;
                sc[r] = m;
                Aq[l * SA + j] = f2bf(m);      // masked score -> A-layout for GEMM2
            }
        }
        rs += sc;                               // nt==4: rows 65..79 exact zeros
    }
    #pragma unroll
    for (int m = 1; m <= 8; m <<= 1) {          // row-sum across the 16 cols
        rs[0] += __shfl_xor(rs[0], m);
        rs[1] += __shfl_xor(rs[1], m);
        rs[2] += __shfl_xor(rs[2], m);
        rs[3] += __shfl_xor(rs[3], m);
    }
    float inv[4];
    #pragma unroll
    for (int r = 0; r < 4; ++r) inv[r] = 1.0f / fmaxf(rs[r], EPSV);

    __syncthreads();   // make this wave's score writes unambiguously visible

    // GEMM2: O = [scores | qf] * [V ; S]
    short8 sc0 = *(const short8*)&Aq[arow + 0 * 32 + quad * 8];
    short8 sc1 = *(const short8*)&Aq[arow + 1 * 32 + quad * 8];
    #pragma unroll
    for (int nt = 0; nt < 4; ++nt) {
        const int brow = (nt * 16 + lrow) * SV;
        floatx4 oacc = {0.f, 0.f, 0.f, 0.f};
        short8 b0 = *(const short8*)&Bv[brow + 0 * 32 + quad * 8];
        oacc = MFMA16(sc0, b0, oacc);
        short8 b1 = *(const short8*)&Bv[brow + 1 * 32 + quad * 8];
        oacc = MFMA16(sc1, b1, oacc);
        #pragma unroll
        for (int ks = 2; ks < 6; ++ks) {
            short8 bf = *(const short8*)&Bv[brow + ks * 32 + quad * 8];
            oacc = MFMA16(a1f[ks - 2], bf, oacc);
        }
        #pragma unroll
        for (int r = 0; r < 4; ++r) {
            int l = l0 + quad * 4 + r;
            out[gbase + (size_t)l * Dd + nt * 16 + lrow] = oacc[r] * inv[r];
        }
    }
}

extern "C" void kernel_launch(void* const* d_in, const int* in_sizes, int n_in,
                              void* d_out, int out_size, void* d_ws, size_t ws_size,
                              hipStream_t stream) {
    const float* q = (const float*)d_in[0];
    const float* k = (const float*)d_in[1];
    const float* v = (const float*)d_in[2];
    float* out = (float*)d_out;
    unsigned short* kfT = (unsigned short*)d_ws;                  // [h][128][1024] bf16
    unsigned short* vT = kfT + (size_t)Hh * 128 * Ll;             // [h][64][1024] bf16
    dim3 grid(NCHUNK, Hh);
    cf_prep<<<grid, 256, 0, stream>>>(k, v, kfT, vT);
    cf_main<<<grid, 256, 0, stream>>>(q, k, kfT, vT, out);
}

// Round 8
// 82.425 us; speedup vs baseline: 1.1208x; 1.0125x over previous
//
#include <hip/hip_runtime.h>

namespace {
constexpr int Hh = 16;
constexpr int Ll = 1024;
constexpr int Dd = 64;
constexpr int Cc = 64;                   // chunk length
constexpr int NCHUNK = Ll / Cc;          // 16
constexpr float PI_HALF = 1.5707963267948966f;
constexpr float EPSV = 1e-6f;
constexpr int KV_ELEMS = 64 * 128;       // bf16 elems per chunk state [d][f]
constexpr size_t KV_TOTAL_E = (size_t)Hh * NCHUNK * KV_ELEMS;
}

typedef __attribute__((ext_vector_type(8))) short short8;
typedef __attribute__((ext_vector_type(4))) float floatx4;

__device__ __forceinline__ unsigned short f2bf(float x) {
    unsigned int u = __float_as_uint(x);
    unsigned int r = u + 0x7fffu + ((u >> 16) & 1u);
    return (unsigned short)(r >> 16);
}
__device__ __forceinline__ float bf2f(unsigned short b) {
    return __uint_as_float(((unsigned int)b) << 16);
}

#define MFMA16(a, b, c) __builtin_amdgcn_mfma_f32_16x16x32_bf16((a), (b), (c), 0, 0, 0)

// ---------------------------------------------------------------------------
// Kernel 1: per (h,c) chunk sums via MFMA (session-verified baseline code).
//   C[f][d] = sum_j kf[j][f] * v[j][d];  ksum[f] via ones column.
// Output staged to LDS as [d][f] then coalesced bf16 store to ws.
__global__ __launch_bounds__(256)
void cf_sums(const float* __restrict__ kin, const float* __restrict__ vin,
             unsigned short* __restrict__ wskv, unsigned short* __restrict__ wsks) {
    const int c = blockIdx.x, h = blockIdx.y;
    const int tid = threadIdx.x;
    constexpr int S1 = 72, SC = 136;
    __shared__ unsigned short Ak[128 * S1];
    __shared__ unsigned short Bv1[80 * S1];
    __shared__ unsigned short Cst[64 * SC];
    __shared__ unsigned short Ks[128];

    const size_t gbase = ((size_t)h * Ll + (size_t)c * Cc) * Dd;
    const float4* k4 = (const float4*)(kin + gbase);
    const float4* v4 = (const float4*)(vin + gbase);
    #pragma unroll
    for (int i = 0; i < 4; ++i) {
        int e4 = i * 256 + tid;
        int j = e4 >> 4, d4 = (e4 & 15) * 4;
        float th = PI_HALF * (float)(c * Cc + j + 1) * (1.0f / (float)Ll);
        float sj, cj; __sincosf(th, &sj, &cj);
        float4 kx = k4[e4];
        float r0 = fmaxf(kx.x, 0.f), r1 = fmaxf(kx.y, 0.f);
        float r2 = fmaxf(kx.z, 0.f), r3 = fmaxf(kx.w, 0.f);
        Ak[(d4 + 0) * S1 + j] = f2bf(r0 * sj);
        Ak[(d4 + 1) * S1 + j] = f2bf(r1 * sj);
        Ak[(d4 + 2) * S1 + j] = f2bf(r2 * sj);
        Ak[(d4 + 3) * S1 + j] = f2bf(r3 * sj);
        Ak[(64 + d4 + 0) * S1 + j] = f2bf(r0 * cj);
        Ak[(64 + d4 + 1) * S1 + j] = f2bf(r1 * cj);
        Ak[(64 + d4 + 2) * S1 + j] = f2bf(r2 * cj);
        Ak[(64 + d4 + 3) * S1 + j] = f2bf(r3 * cj);
        float4 vx = v4[e4];
        Bv1[(d4 + 0) * S1 + j] = f2bf(vx.x);
        Bv1[(d4 + 1) * S1 + j] = f2bf(vx.y);
        Bv1[(d4 + 2) * S1 + j] = f2bf(vx.z);
        Bv1[(d4 + 3) * S1 + j] = f2bf(vx.w);
    }
    if (tid < 64) Bv1[64 * S1 + tid] = 0x3F80;           // ones column (bf16 1.0)
    if (tid >= 64 && tid < 72) Bv1[64 * S1 + tid] = 0;   // pad of ones row
    #pragma unroll
    for (int i = 0; i < 3; ++i) {                        // zero rows 65..79
        int z = i * 256 + tid;
        if (z < 540) ((unsigned int*)Bv1)[(65 * S1) / 2 + z] = 0u;
    }
    __syncthreads();

    const int wave = tid >> 6, lane = tid & 63;
    const int lrow = lane & 15, quad = lane >> 4;
    #pragma unroll
    for (int t = 0; t < 2; ++t) {
        const int ft = wave * 2 + t;                     // f-tile 0..7
        short8 af[2];
        #pragma unroll
        for (int ks = 0; ks < 2; ++ks)
            af[ks] = *(const short8*)&Ak[(ft * 16 + lrow) * S1 + ks * 32 + quad * 8];
        #pragma unroll
        for (int nt = 0; nt < 5; ++nt) {
            floatx4 acc = {0.f, 0.f, 0.f, 0.f};
            #pragma unroll
            for (int ks = 0; ks < 2; ++ks) {
                short8 bf = *(const short8*)&Bv1[(nt * 16 + lrow) * S1 + ks * 32 + quad * 8];
                acc = MFMA16(af[ks], bf, acc);
            }
            ushort4 pk = make_ushort4(f2bf(acc[0]), f2bf(acc[1]), f2bf(acc[2]), f2bf(acc[3]));
            if (nt < 4) {
                // C[f][d] -> Cst[d][f]
                *(ushort4*)&Cst[(nt * 16 + lrow) * SC + ft * 16 + quad * 4] = pk;
            } else if (lrow == 0) {
                *(ushort4*)&Ks[ft * 16 + quad * 4] = pk;  // ksum column (n=64)
            }
        }
    }
    __syncthreads();

    unsigned short* kvout = wskv + (size_t)(h * NCHUNK + c) * KV_ELEMS;
    #pragma unroll
    for (int i = 0; i < 4; ++i) {
        int idx = i * 256 + tid;
        int row = idx >> 4, c8 = (idx & 15) * 8;
        *(uint4*)(kvout + row * 128 + c8) = *(const uint4*)&Cst[row * SC + c8];
    }
    if (tid < 16)
        *(uint4*)(wsks + (size_t)(h * NCHUNK + c) * 128 + tid * 8) =
            *(const uint4*)&Ks[tid * 8];
}

// ---------------------------------------------------------------------------
// Kernel 2: per (h,c) output. Exclusive prefix state = fp32 VALU sum of the
// c bf16 chunk-states (2-deep prefetch, no barriers, no scan kernel). Then
// the verified staging + GEMM1 (scores+denom) + GEMM2 epilogue.
__global__ __launch_bounds__(256)
void cf_out2(const float* __restrict__ qin, const float* __restrict__ kin,
             const float* __restrict__ vin,
             const unsigned short* __restrict__ wskv,
             const unsigned short* __restrict__ wsks,
             float* __restrict__ out) {
    const int c = blockIdx.x, h = blockIdx.y;
    const int tid = threadIdx.x;
    constexpr int SA = 200, SB = 136, SV = 200;
    __shared__ unsigned short Aq[64 * SA];   // [l][0..63 scores | 64..191 qf]
    __shared__ unsigned short Bk[80 * SB];   // [n=j][k=f]; row 64 = ksum; 65..79 = 0
    __shared__ unsigned short Bv[64 * SV];   // [n=d][0..63 V^T | 64..191 S]

    const int wave = tid >> 6, lane = tid & 63;
    const int lrow = lane & 15, quad = lane >> 4;

    #pragma unroll
    for (int i = 0; i < 4; ++i) {            // zero Bk rows 65..79
        int z = i * 256 + tid;
        if (z < 1020) ((unsigned int*)Bk)[(65 * SB) / 2 + z] = 0u;
    }

    // ---- staging q,k,v of own chunk (verified) ----
    const size_t gbase = ((size_t)h * Ll + (size_t)c * Cc) * Dd;
    const float4* q4 = (const float4*)(qin + gbase);
    const float4* k4 = (const float4*)(kin + gbase);
    const float4* v4 = (const float4*)(vin + gbase);
    #pragma unroll
    for (int i = 0; i < 4; ++i) {
        int e4 = i * 256 + tid;
        int j = e4 >> 4, d4 = (e4 & 15) * 4;
        float th = PI_HALF * (float)(c * Cc + j + 1) * (1.0f / (float)Ll);
        float sj, cj; __sincosf(th, &sj, &cj);
        float4 qv = q4[e4];
        float q0 = fmaxf(qv.x, 0.f), q1 = fmaxf(qv.y, 0.f);
        float q2 = fmaxf(qv.z, 0.f), q3 = fmaxf(qv.w, 0.f);
        *(ushort4*)&Aq[j * SA + 64 + d4] =
            make_ushort4(f2bf(q0 * sj), f2bf(q1 * sj), f2bf(q2 * sj), f2bf(q3 * sj));
        *(ushort4*)&Aq[j * SA + 128 + d4] =
            make_ushort4(f2bf(q0 * cj), f2bf(q1 * cj), f2bf(q2 * cj), f2bf(q3 * cj));
        float4 kx = k4[e4];
        float k0 = fmaxf(kx.x, 0.f), k1 = fmaxf(kx.y, 0.f);
        float k2 = fmaxf(kx.z, 0.f), k3 = fmaxf(kx.w, 0.f);
        *(ushort4*)&Bk[j * SB + d4] =
            make_ushort4(f2bf(k0 * sj), f2bf(k1 * sj), f2bf(k2 * sj), f2bf(k3 * sj));
        *(ushort4*)&Bk[j * SB + 64 + d4] =
            make_ushort4(f2bf(k0 * cj), f2bf(k1 * cj), f2bf(k2 * cj), f2bf(k3 * cj));
        float4 vx = v4[e4];
        Bv[(d4 + 0) * SV + j] = f2bf(vx.x);
        Bv[(d4 + 1) * SV + j] = f2bf(vx.y);
        Bv[(d4 + 2) * SV + j] = f2bf(vx.z);
        Bv[(d4 + 3) * SV + j] = f2bf(vx.w);
    }

    // ---- exclusive prefix: fp32 sum of chunk-states 0..c-1 ----
    // state layout [d][f]: thread t owns d = t>>2, f = (t&3)*32 .. +31
    float facc[32];
    #pragma unroll
    for (int e = 0; e < 32; ++e) facc[e] = 0.f;
    const unsigned short* sbase = wskv + (size_t)h * NCHUNK * KV_ELEMS + tid * 32;
    if (c > 0) {
        short8 cur[4], nxt[4];
        #pragma unroll
        for (int i = 0; i < 4; ++i)
            cur[i] = *(const short8*)(sbase + i * 8);
        if (c > 1) {
            #pragma unroll
            for (int i = 0; i < 4; ++i)
                nxt[i] = *(const short8*)(sbase + KV_ELEMS + i * 8);
        }
        for (int cc = 0; cc < c; ++cc) {
            short8 fut[4];
            if (cc + 2 < c) {
                #pragma unroll
                for (int i = 0; i < 4; ++i)
                    fut[i] = *(const short8*)(sbase + (size_t)(cc + 2) * KV_ELEMS + i * 8);
            }
            #pragma unroll
            for (int i = 0; i < 4; ++i)
                #pragma unroll
                for (int e = 0; e < 8; ++e)
                    facc[i * 8 + e] += bf2f((unsigned short)cur[i][e]);
            #pragma unroll
            for (int i = 0; i < 4; ++i) { cur[i] = nxt[i]; nxt[i] = fut[i]; }
        }
    }
    float kacc = 0.f;
    if (tid < 128) {
        const unsigned short* kb = wsks + (size_t)h * NCHUNK * 128 + tid;
        for (int cc = 0; cc < c; ++cc) kacc += bf2f(kb[cc * 128]);
    }

    // ---- dump state -> Bv[d][64+f], ksum -> Bk row 64 ----
    {
        const int d = tid >> 2, f0 = (tid & 3) * 32;
        #pragma unroll
        for (int e8 = 0; e8 < 8; ++e8) {
            *(ushort4*)&Bv[d * SV + 64 + f0 + e8 * 4] =
                make_ushort4(f2bf(facc[e8 * 4 + 0]), f2bf(facc[e8 * 4 + 1]),
                             f2bf(facc[e8 * 4 + 2]), f2bf(facc[e8 * 4 + 3]));
        }
        if (tid < 128) Bk[64 * SB + tid] = f2bf(kacc);
    }
    __syncthreads();

    const int l0 = wave * 16;
    const int arow = (l0 + lrow) * SA;

    // ---- GEMM1: scores + denominator (verified) ----
    short8 a1f[4];
    #pragma unroll
    for (int ks = 0; ks < 4; ++ks)
        a1f[ks] = *(const short8*)&Aq[arow + 64 + ks * 32 + quad * 8];
    floatx4 rs = {0.f, 0.f, 0.f, 0.f};
    #pragma unroll
    for (int nt = 0; nt < 5; ++nt) {
        floatx4 sc = {0.f, 0.f, 0.f, 0.f};
        #pragma unroll
        for (int ks = 0; ks < 4; ++ks) {
            short8 bf = *(const short8*)&Bk[(nt * 16 + lrow) * SB + ks * 32 + quad * 8];
            sc = MFMA16(a1f[ks], bf, sc);
        }
        if (nt < 4) {
            int j = nt * 16 + lrow;
            #pragma unroll
            for (int r = 0; r < 4; ++r) {
                int l = l0 + quad * 4 + r;
                float m = (j <= l) ? sc[r] : 0.f;
                sc[r] = m;
                Aq[l * SA + j] = f2bf(m);      // masked score -> A-layout for GEMM2
            }
        }
        rs += sc;                               // nt==4: rows 65..79 exact zeros
    }
    #pragma unroll
    for (int m = 1; m <= 8; m <<= 1) {          // row-sum across the 16 cols
        rs[0] += __shfl_xor(rs[0], m);
        rs[1] += __shfl_xor(rs[1], m);
        rs[2] += __shfl_xor(rs[2], m);
        rs[3] += __shfl_xor(rs[3], m);
    }
    float inv[4];
    #pragma unroll
    for (int r = 0; r < 4; ++r) inv[r] = 1.0f / fmaxf(rs[r], EPSV);

    __syncthreads();   // make this wave's score writes unambiguously visible

    // ---- GEMM2: O = [scores | qf] * [V ; S] (verified) ----
    short8 sc0 = *(const short8*)&Aq[arow + 0 * 32 + quad * 8];
    short8 sc1 = *(const short8*)&Aq[arow + 1 * 32 + quad * 8];
    #pragma unroll
    for (int nt = 0; nt < 4; ++nt) {
        const int brow = (nt * 16 + lrow) * SV;
        floatx4 oacc = {0.f, 0.f, 0.f, 0.f};
        short8 b0 = *(const short8*)&Bv[brow + 0 * 32 + quad * 8];
        oacc = MFMA16(sc0, b0, oacc);
        short8 b1 = *(const short8*)&Bv[brow + 1 * 32 + quad * 8];
        oacc = MFMA16(sc1, b1, oacc);
        #pragma unroll
        for (int ks = 2; ks < 6; ++ks) {
            short8 bf = *(const short8*)&Bv[brow + ks * 32 + quad * 8];
            oacc = MFMA16(a1f[ks - 2], bf, oacc);
        }
        #pragma unroll
        for (int r = 0; r < 4; ++r) {
            int l = l0 + quad * 4 + r;
            out[gbase + (size_t)l * Dd + nt * 16 + lrow] = oacc[r] * inv[r];
        }
    }
}

extern "C" void kernel_launch(void* const* d_in, const int* in_sizes, int n_in,
                              void* d_out, int out_size, void* d_ws, size_t ws_size,
                              hipStream_t stream) {
    const float* q = (const float*)d_in[0];
    const float* k = (const float*)d_in[1];
    const float* v = (const float*)d_in[2];
    float* out = (float*)d_out;
    unsigned short* wskv = (unsigned short*)d_ws;             // [h][c][d][f] bf16
    unsigned short* wsks = wskv + KV_TOTAL_E;                 // [h][c][128] bf16
    dim3 grid(NCHUNK, Hh);
    cf_sums<<<grid, 256, 0, stream>>>(k, v, wskv, wsks);
    cf_out2<<<grid, 256, 0, stream>>>(q, k, v, wskv, wsks, out);
}